// Round 14
// baseline (140.264 us; speedup 1.0000x reference)
//
#include <hip/hip_runtime.h>
#include <hip/hip_fp16.h>

#define NN 100000   // nodes
#define NE 1000000  // edges
#define FD 64       // feature dim
#define CHK 64      // nodes per block tile in k_l1
#define NBLK 98     // scan blocks: ceil(NN/1024)

typedef _Float16 f16x2 __attribute__((ext_vector_type(2)));

#if defined(__has_builtin)
#if __has_builtin(__builtin_amdgcn_fdot2)
#define HAVE_FDOT2 1
#endif
#endif

__device__ __forceinline__ float fdot2f(__half2 a, __half2 b, float c) {
#ifdef HAVE_FDOT2
    return __builtin_amdgcn_fdot2(__builtin_bit_cast(f16x2, a),
                                  __builtin_bit_cast(f16x2, b), c, false);
#else
    const float2 af = __half22float2(a), bf = __half22float2(b);
    return c + af.x * bf.x + af.y * bf.y;
#endif
}

// ws layout (4-byte units):
//   deg      : [0, NN)              int
//   rowstart : [NN, 2NN)            int   (exclusive scan of deg)
//   partial  : [2NN, 2NN+128)       int   (scan block sums)
//   rank     : [2NN+128, +NE)       int   (edge rank within its dst row)
//   csr      : [2NN+128+NE, +NE)    int   (pre-shifted byte offsets src<<7)
//   pq       : next, 4NN floats
//   wth      : next, 2*2048 half2   (W1l^T, W1r^T packed f16 [j2][k])
//   xh       : next, (NN+1)*64 halves (f16 copy of x; row NN = zeros)
// total ~ 23.4 MB

#define OFF_DEG 0
#define OFF_ROW (NN)
#define OFF_PAR (2 * NN)
#define OFF_RANK (2 * NN + 128)
#define OFF_CSR (2 * NN + 128 + NE)
#define OFF_PQ  (2 * NN + 128 + 2 * NE)
#define OFF_WTH (OFF_PQ + 4 * NN)        // 2*2048 uints
#define OFF_XH  (OFF_WTH + 2 * 2048)     // 16B-aligned (all terms %4==0)

struct alignas(16) H8 { __half2 h[4]; };

#define NA (NE / 16)          // 62500 atomic threads (16 edges each)
#define NC (NN * FD / 8)      // 800000 cast threads

// ---------------------------------------------------------------------------
// K1 (fused, disjoint thread ranges):
//   [0, NA)         : deg atomics + rank, 16 edges/thread: 4 int4 loads ->
//                     16 INDEPENDENT returning atomics in flight -> 4 stores.
//   [NA, +NC)       : x -> f16 copy (8 elems/thread)
//   next 8          : zero pad row
//   next 2048       : pack W1l^T,W1r^T to f16 half2 [j2][k]
__global__ void k_pc(const int* __restrict__ ei, int* __restrict__ deg,
                     int* __restrict__ rank,
                     const float* __restrict__ x, __half* __restrict__ xh,
                     const float* __restrict__ W1l, const float* __restrict__ W1r,
                     __half2* __restrict__ wt1lh, __half2* __restrict__ wt1rh) {
    const int tid = blockIdx.x * blockDim.x + threadIdx.x;
    if (tid < NA) {
        const int4* dstv = (const int4*)(ei + NE);
        int4* rankv = (int4*)rank;
        int4 dd[4];
#pragma unroll
        for (int u = 0; u < 4; ++u) dd[u] = dstv[tid * 4 + u];
        int4 rr[4];
#pragma unroll
        for (int u = 0; u < 4; ++u) {
            rr[u].x = atomicAdd(&deg[dd[u].x], 1);
            rr[u].y = atomicAdd(&deg[dd[u].y], 1);
            rr[u].z = atomicAdd(&deg[dd[u].z], 1);
            rr[u].w = atomicAdd(&deg[dd[u].w], 1);
        }
#pragma unroll
        for (int u = 0; u < 4; ++u) rankv[tid * 4 + u] = rr[u];
    } else if (tid < NA + NC) {
        const int i = tid - NA;
        const float4 a = *((const float4*)x + (size_t)i * 2);
        const float4 b = *((const float4*)x + (size_t)i * 2 + 1);
        H8 o;
        o.h[0] = __floats2half2_rn(a.x, a.y);
        o.h[1] = __floats2half2_rn(a.z, a.w);
        o.h[2] = __floats2half2_rn(b.x, b.y);
        o.h[3] = __floats2half2_rn(b.z, b.w);
        *((H8*)xh + i) = o;
    } else if (tid < NA + NC + 8) {
        H8 z;
        z.h[0] = z.h[1] = z.h[2] = z.h[3] = __float2half2_rn(0.f);
        *((H8*)(xh + (size_t)NN * FD) + (tid - NA - NC)) = z;
    } else if (tid < NA + NC + 8 + 2048) {
        const int i = tid - (NA + NC + 8);   // j2*64 + k
        const int j2 = i >> 6, k = i & 63;
        wt1lh[i] = __floats2half2_rn(W1l[k * FD + 2 * j2], W1l[k * FD + 2 * j2 + 1]);
        wt1rh[i] = __floats2half2_rn(W1r[k * FD + 2 * j2], W1r[k * FD + 2 * j2 + 1]);
    }
}

// ---------------------------------------------------------------------------
// K2a: per-block (1024-elem) sums of deg -> partial[b]
__global__ __launch_bounds__(256) void k_scanA(const int* __restrict__ deg,
                                               int* __restrict__ partial) {
    __shared__ int lds[256];
    int t = threadIdx.x;
    int base = blockIdx.x * 1024 + t * 4;
    int s_t = 0;
    if (base < NN) {  // NN % 4 == 0
        int4 v = *(const int4*)(deg + base);
        s_t = v.x + v.y + v.z + v.w;
    }
    lds[t] = s_t;
    __syncthreads();
    for (int s = 128; s; s >>= 1) {
        if (t < s) lds[t] += lds[t + s];
        __syncthreads();
    }
    if (t == 0) partial[blockIdx.x] = lds[0];
}

// K2b: block offset + intra-block exclusive scan -> rowstart[i]
__global__ __launch_bounds__(256) void k_scanB(const int* __restrict__ deg,
                                               const int* __restrict__ partial,
                                               int* __restrict__ rowstart) {
    __shared__ int lds[256];
    int t = threadIdx.x, b = blockIdx.x;
    lds[t] = (t < b && t < NBLK) ? partial[t] : 0;
    __syncthreads();
    for (int s = 128; s; s >>= 1) {
        if (t < s) lds[t] += lds[t + s];
        __syncthreads();
    }
    int bo = lds[0];
    __syncthreads();

    int base = b * 1024 + t * 4;
    int4 v = make_int4(0, 0, 0, 0);
    if (base < NN) v = *(const int4*)(deg + base);
    int s_t = v.x + v.y + v.z + v.w;

    lds[t] = s_t;
    __syncthreads();
    for (int off = 1; off < 256; off <<= 1) {
        int v2 = lds[t];
        if (t >= off) v2 += lds[t - off];
        __syncthreads();
        lds[t] = v2;
        __syncthreads();
    }
    int excl = lds[t] - s_t;
    if (base < NN) {
        int r = bo + excl;
        int4 out;
        out.x = r;
        out.y = r + v.x;
        out.z = r + v.x + v.y;
        out.w = r + v.x + v.y + v.z;
        *(int4*)(rowstart + base) = out;
    }
}

// ---------------------------------------------------------------------------
// K3: csr scatter (src<<7 byte offsets) + edge_index float conversion.
__global__ void k_build(const int* __restrict__ ei, const int* __restrict__ rowstart,
                        const int* __restrict__ rank, int* __restrict__ csr,
                        float* __restrict__ edge_out) {
    const int i = blockIdx.x * blockDim.x + threadIdx.x;
    if (i >= NE / 4) return;
    const int4 s = *((const int4*)ei + i);
    const int4 d = *((const int4*)(ei + NE) + i);
    const int4 r = *((const int4*)rank + i);
    csr[rowstart[d.x] + r.x] = s.x << 7;
    csr[rowstart[d.y] + r.y] = s.y << 7;
    csr[rowstart[d.z] + r.z] = s.z << 7;
    csr[rowstart[d.w] + r.w] = s.w << 7;
    float4 fs, fd;
    fs.x = (float)s.x; fs.y = (float)s.y; fs.z = (float)s.z; fs.w = (float)s.w;
    fd.x = (float)d.x; fd.y = (float)d.y; fd.z = (float)d.z; fd.w = (float)d.w;
    *((float4*)edge_out + i) = fs;
    *((float4*)(edge_out + NE) + i) = fd;
}

// ---------------------------------------------------------------------------
// K4: fused layer-1, 64-node tile per block (8 waves, 512 threads).
//  phase A: 8 groups of 8 lanes; group owns one node; 16-DEEP batches: two
//    id-loads per chunk (slots jb+sl, jb+8+sl), 16 row-loads in flight before
//    sched_barrier. One chunk covers deg<=16 (~97% of nodes). Invalid slots
//    hit the zero row (exact, maskless, L1-resident).
//  phase B: packed half2 j-pairs + v_dot2_f32_f16 (2 MAC/instr, f32 accum).
__global__ __launch_bounds__(512, 4) void k_l1(
    const int* __restrict__ csr, const int* __restrict__ rowstart,
    const int* __restrict__ deg, const __half* __restrict__ xh,
    const __half2* __restrict__ wt1lh, const float* __restrict__ b1,
    const __half2* __restrict__ wt1rh,
    const float* __restrict__ W2l, const float* __restrict__ b2,
    const float* __restrict__ W2r,
    float* __restrict__ pq) {
    __shared__ __half2 sH[FD / 2][CHK + 1];   // 8.3 KB
    __shared__ __half2 xH[FD / 2][CHK + 1];   // 8.3 KB
    __shared__ float pacc[4 * CHK];           // 1 KB
    const int lane = threadIdx.x & 63;
    const int wid = threadIdx.x >> 6;   // 0..7
    const int g = lane >> 3;            // group 0..7
    const int sl = lane & 7;            // lane within group
    const int gb = g << 3;              // group base lane
    const int base = blockIdx.x * CHK;
    const char* xb = (const char*)xh;
    const unsigned slb = (unsigned)(sl << 4);   // 16B per lane
    const int ZOFF = NN << 7;                   // zero-row byte offset

    if (threadIdx.x < 4 * CHK) pacc[threadIdx.x] = 0.f;

    // ---- phase A: one node per group (8 nodes per wave) ----
    const int nl = wid * 8 + g;         // 0..63
    const int n = base + nl;
    const bool ok = n < NN;
    const int nn = ok ? n : NN - 1;
    const int d = deg[nn];              // group-uniform
    const int rs = rowstart[nn];

    int dmax = d;
    dmax = max(dmax, __shfl_xor(dmax, 8));
    dmax = max(dmax, __shfl_xor(dmax, 16));
    dmax = max(dmax, __shfl_xor(dmax, 32));
    const int nch = __builtin_amdgcn_readfirstlane((dmax + 15) >> 4);

    H8 acc;
    acc.h[0] = acc.h[1] = acc.h[2] = acc.h[3] = __float2half2_rn(0.f);

    for (int c = 0; c < nch; ++c) {
        const int jb = c << 4;
        const int ia0 = min(rs + jb + sl, NE - 1);
        const int ia1 = min(rs + jb + 8 + sl, NE - 1);
        const int raw0 = csr[ia0];                        // pre-shifted src<<7
        const int raw1 = csr[ia1];
        const int offs0 = (jb + sl < d) ? raw0 : ZOFF;    // invalid -> zero row
        const int offs1 = (jb + 8 + sl < d) ? raw1 : ZOFF;
        H8 buf[16];
#pragma unroll
        for (int t = 0; t < 8; ++t) {
            const unsigned ob = (unsigned)__shfl(offs0, gb + t);
            buf[t] = *(const H8*)(xb + (size_t)(ob + slb));
        }
#pragma unroll
        for (int t = 0; t < 8; ++t) {
            const unsigned ob = (unsigned)__shfl(offs1, gb + t);
            buf[8 + t] = *(const H8*)(xb + (size_t)(ob + slb));
        }
        __builtin_amdgcn_sched_barrier(0);  // keep 16 row-loads in flight
#pragma unroll
        for (int t = 0; t < 16; ++t) {
            acc.h[0] = __hadd2(acc.h[0], buf[t].h[0]);
            acc.h[1] = __hadd2(acc.h[1], buf[t].h[1]);
            acc.h[2] = __hadd2(acc.h[2], buf[t].h[2]);
            acc.h[3] = __hadd2(acc.h[3], buf[t].h[3]);
        }
    }

    if (ok) {
        const __half2 hinv = __float2half2_rn(1.0f / (float)max(d, 1));
        const H8 xv = *(const H8*)(xb + (size_t)(((unsigned)nn << 7) + slb));
#pragma unroll
        for (int t = 0; t < 4; ++t) {
            sH[sl * 4 + t][nl] = __hmul2(acc.h[t], hinv);
            xH[sl * 4 + t][nl] = xv.h[t];
        }
    }
    __syncthreads();

    // ---- phase B: lane = node, k-slice [kbase, kbase+8), packed j-pairs ----
    const int kbase = __builtin_amdgcn_readfirstlane(wid * 8);
    float h[8];
#pragma unroll
    for (int t = 0; t < 8; ++t) h[t] = b1[kbase + t];
#pragma unroll 4
    for (int j2 = 0; j2 < FD / 2; ++j2) {
        const __half2 sj = sH[j2][lane];
        const __half2 xj = xH[j2][lane];
        const __half2* wl = wt1lh + j2 * FD + kbase;   // wave-uniform
        const __half2* wr = wt1rh + j2 * FD + kbase;
#pragma unroll
        for (int t = 0; t < 8; ++t) {
            h[t] = fdot2f(sj, wl[t], h[t]);
            h[t] = fdot2f(xj, wr[t], h[t]);
        }
    }

    float p0 = 0.f, p1 = 0.f, q0 = 0.f, q1 = 0.f;
#pragma unroll
    for (int t = 0; t < 8; ++t) {
        const float r = fmaxf(h[t], 0.f);
        p0 += r * W2l[kbase + t];
        p1 += r * W2l[FD + kbase + t];
        q0 += r * W2r[kbase + t];
        q1 += r * W2r[FD + kbase + t];
    }
    atomicAdd(&pacc[0 * CHK + lane], p0);
    atomicAdd(&pacc[1 * CHK + lane], p1);
    atomicAdd(&pacc[2 * CHK + lane], q0);
    atomicAdd(&pacc[3 * CHK + lane], q1);
    __syncthreads();

    // ---- write pq: thread t -> (node t>>2, comp t&3), coalesced ----
    {
        const int t = threadIdx.x;
        if (t < 4 * CHK) {
            const int nw = base + (t >> 2);
            if (nw < NN) {
                const int c = t & 3;
                float v = pacc[c * CHK + (t >> 2)];
                if (c == 2) v += b2[0];
                if (c == 3) v += b2[1];
                pq[(size_t)nw * 4 + c] = v;
            }
        }
    }
}

// ---------------------------------------------------------------------------
// K5: layer-2 mean aggregation of p + final add. 16 lanes per node,
//     4 nodes per wave. csr holds src<<7; pq byte offset = src*16 = v>>3.
__global__ void k_l2(const int* __restrict__ csr, const int* __restrict__ rowstart,
                     const int* __restrict__ deg, const float* __restrict__ pq,
                     float* __restrict__ out) {
    const int gw = (blockIdx.x * blockDim.x + threadIdx.x) >> 6;
    const int lane = threadIdx.x & 63;
    const int sub = lane >> 4;   // node within wave
    const int sl = lane & 15;    // lane within 16-group
    const int n = gw * 4 + sub;
    if (n >= NN) return;
    const int rs = rowstart[n];
    const int d = deg[n];
    const char* pb = (const char*)pq;
    float a0 = 0.f, a1 = 0.f;
    for (int i = sl; i < d; i += 16) {
        const unsigned v = (unsigned)csr[rs + i];
        const float2 p = *(const float2*)(pb + (size_t)(v >> 3));
        a0 += p.x;
        a1 += p.y;
    }
#pragma unroll
    for (int off = 8; off; off >>= 1) {
        a0 += __shfl_xor(a0, off);
        a1 += __shfl_xor(a1, off);
    }
    if (sl == 0) {
        const float inv = 1.0f / (float)max(d, 1);
        const float2 q = *(const float2*)(pq + 4 * (size_t)n + 2);
        *(float2*)(out + 2 * (size_t)n) = make_float2(a0 * inv + q.x, a1 * inv + q.y);
    }
}

// ---------------------------------------------------------------------------
extern "C" void kernel_launch(void* const* d_in, const int* in_sizes, int n_in,
                              void* d_out, int out_size, void* d_ws, size_t ws_size,
                              hipStream_t stream) {
    const float* x   = (const float*)d_in[0];
    const int*   ei  = (const int*)d_in[1];
    const float* W1l = (const float*)d_in[2];
    const float* b1  = (const float*)d_in[3];
    const float* W1r = (const float*)d_in[4];
    const float* W2l = (const float*)d_in[5];
    const float* b2  = (const float*)d_in[6];
    const float* W2r = (const float*)d_in[7];

    float* out      = (float*)d_out;   // N*2 floats
    float* edge_out = out + 2 * NN;    // 2*E floats (edge_index as float)

    int*    wsi      = (int*)d_ws;
    int*    deg      = wsi + OFF_DEG;
    int*    rowstart = wsi + OFF_ROW;
    int*    partial  = wsi + OFF_PAR;
    int*    rank     = wsi + OFF_RANK;
    int*    csr      = wsi + OFF_CSR;
    float*  pq       = (float*)d_ws + OFF_PQ;
    __half2* wt1lh   = (__half2*)((float*)d_ws + OFF_WTH);
    __half2* wt1rh   = wt1lh + 2048;
    __half*  xh      = (__half*)((float*)d_ws + OFF_XH);

    hipMemsetAsync(deg, 0, (size_t)NN * sizeof(int), stream);

    const int npc = NA + NC + 8 + 2048;
    k_pc<<<(npc + 255) / 256, 256, 0, stream>>>(ei, deg, rank, x, xh,
                                                W1l, W1r, wt1lh, wt1rh);
    k_scanA<<<NBLK, 256, 0, stream>>>(deg, partial);
    k_scanB<<<NBLK, 256, 0, stream>>>(deg, partial, rowstart);
    k_build<<<(NE / 4 + 255) / 256, 256, 0, stream>>>(ei, rowstart, rank, csr,
                                                      edge_out);
    k_l1<<<(NN + CHK - 1) / CHK, 512, 0, stream>>>(csr, rowstart, deg, xh,
                                                   wt1lh, b1, wt1rh,
                                                   W2l, b2, W2r, pq);
    k_l2<<<((NN + 3) / 4 * 64 + 255) / 256, 256, 0, stream>>>(
        csr, rowstart, deg, pq, out);
}